// Round 3
// baseline (968.040 us; speedup 1.0000x reference)
//
#include <hip/hip_runtime.h>
#include <hip/hip_bf16.h>
#include <math.h>

typedef unsigned short u16;
typedef __bf16 bf16x8 __attribute__((ext_vector_type(8)));
typedef float floatx4 __attribute__((ext_vector_type(4)));

#define LORA_SCALING 2.0f   // alpha 32 / rank 16

// Swizzled intermediate layout: within each row and each 64-col (8x16B-chunk) group,
// stored chunk c8 holds original chunk c8 ^ (row & 7). This makes the GEMM's
// global_load_lds source perfectly linear (coalesced DMA) while the LDS tile ends up
// XOR-swizzled -> conflict-free ds_read_b128 fragment loads.

// ---------- helpers ----------
__device__ __forceinline__ u16 f2bf(float f) {
  unsigned u = __float_as_uint(f);
  u += 0x7fffu + ((u >> 16) & 1u);   // round-to-nearest-even
  return (u16)(u >> 16);
}
__device__ __forceinline__ float bflo(unsigned u) { return __uint_as_float(u << 16); }
__device__ __forceinline__ float bfhi(unsigned u) { return __uint_as_float(u & 0xffff0000u); }

// ---------- ws scale-slot zeroing (ws is poisoned 0xAA before every launch) ----------
__global__ void zero_ws_kernel(unsigned* p) {
  if (threadIdx.x < 16) p[threadIdx.x] = 0u;
}

// ---------- per-tensor absmax ----------
__global__ void absmax_kernel(const float* __restrict__ w, long long n4, unsigned* __restrict__ out) {
  long long i = (long long)blockIdx.x * blockDim.x + threadIdx.x;
  long long stride = (long long)gridDim.x * blockDim.x;
  float m = 0.f;
  for (; i < n4; i += stride) {
    float4 v = ((const float4*)w)[i];
    m = fmaxf(m, fmaxf(fmaxf(fabsf(v.x), fabsf(v.y)), fmaxf(fabsf(v.z), fabsf(v.w))));
  }
#pragma unroll
  for (int o = 32; o > 0; o >>= 1) m = fmaxf(m, __shfl_xor(m, o, 64));
  __shared__ float sm[8];
  int lane = threadIdx.x & 63, wv = threadIdx.x >> 6;
  if (lane == 0) sm[wv] = m;
  __syncthreads();
  if (threadIdx.x == 0) {
    float mm = sm[0];
    int nw = blockDim.x >> 6;
    for (int j = 1; j < nw; ++j) mm = fmaxf(mm, sm[j]);
    atomicMax(out, __float_as_uint(mm));   // nonneg floats: uint order == float order
  }
}

// ---------- fake-quant W (fp32) -> bf16, XOR-swizzled layout ----------
// one 16B output chunk (8 elems) per thread-iter; kshift3 = log2(K/8) (chunks per row)
__global__ void quant_swz_kernel(const float* __restrict__ w, const unsigned* __restrict__ amax,
                                 u16* __restrict__ wq, long long nchunk, int kshift3) {
  float am = __uint_as_float(*amax);
  float scale = am * (1.0f / 127.0f);
  float inv = 127.0f / am;
  long long c = (long long)blockIdx.x * blockDim.x + threadIdx.x;
  long long stride = (long long)gridDim.x * blockDim.x;
  for (; c < nchunk; c += stride) {
    long long row = c >> kshift3;
    long long src = (c & ~7ll) | ((c ^ row) & 7);   // swizzled source chunk
    const float4* s = (const float4*)(w + src * 8);
    float4 a = s[0], b = s[1];
    union { u16 h[8]; uint4 v; } o;
    o.h[0] = f2bf(fminf(fmaxf(rintf(a.x * inv), -128.f), 127.f) * scale);
    o.h[1] = f2bf(fminf(fmaxf(rintf(a.y * inv), -128.f), 127.f) * scale);
    o.h[2] = f2bf(fminf(fmaxf(rintf(a.z * inv), -128.f), 127.f) * scale);
    o.h[3] = f2bf(fminf(fmaxf(rintf(a.w * inv), -128.f), 127.f) * scale);
    o.h[4] = f2bf(fminf(fmaxf(rintf(b.x * inv), -128.f), 127.f) * scale);
    o.h[5] = f2bf(fminf(fmaxf(rintf(b.y * inv), -128.f), 127.f) * scale);
    o.h[6] = f2bf(fminf(fmaxf(rintf(b.z * inv), -128.f), 127.f) * scale);
    o.h[7] = f2bf(fminf(fmaxf(rintf(b.w * inv), -128.f), 127.f) * scale);
    ((uint4*)wq)[c] = o.v;
  }
}

// ---------- fp32 -> bf16, XOR-swizzled layout ----------
__global__ void f2bf_swz_kernel(const float* __restrict__ x, u16* __restrict__ xb,
                                long long nchunk, int kshift3) {
  long long c = (long long)blockIdx.x * blockDim.x + threadIdx.x;
  long long stride = (long long)gridDim.x * blockDim.x;
  for (; c < nchunk; c += stride) {
    long long row = c >> kshift3;
    long long src = (c & ~7ll) | ((c ^ row) & 7);
    const float4* s = (const float4*)(x + src * 8);
    float4 a = s[0], b = s[1];
    union { u16 h[8]; uint4 v; } o;
    o.h[0] = f2bf(a.x); o.h[1] = f2bf(a.y); o.h[2] = f2bf(a.z); o.h[3] = f2bf(a.w);
    o.h[4] = f2bf(b.x); o.h[5] = f2bf(b.y); o.h[6] = f2bf(b.z); o.h[7] = f2bf(b.w);
    ((uint4*)xb)[c] = o.v;
  }
}

// ---------- LoRA t = X(bf16, swizzled) @ A^T(fp32), rank 16 ----------
__global__ void lora_t_kernel(const u16* __restrict__ X, const float* __restrict__ A,
                              float* __restrict__ T, int K) {
  int r = threadIdx.x & 15;
  int mi = threadIdx.x >> 4;
  long long row = (long long)blockIdx.x * 16 + mi;
  int rp = (int)row & 7;
  const u16* xp = X + row * K;
  const float* ap = A + (long long)r * K;
  float acc = 0.f;
  for (int k = 0; k < K; k += 8) {
    int kaddr = (k & ~63) | ((((k >> 3) ^ rp) & 7) << 3);   // swizzled source
    uint4 xu = *(const uint4*)(xp + kaddr);
    float4 a0 = *(const float4*)(ap + k);
    float4 a1 = *(const float4*)(ap + k + 4);
    acc += bflo(xu.x) * a0.x + bfhi(xu.x) * a0.y + bflo(xu.y) * a0.z + bfhi(xu.y) * a0.w;
    acc += bflo(xu.z) * a1.x + bfhi(xu.z) * a1.y + bflo(xu.w) * a1.z + bfhi(xu.w) * a1.w;
  }
  T[row * 16 + r] = acc;
}

// ---------- staging: one 128x64 bf16 tile pair (A+B), LINEAR lane->chunk DMA ----------
__device__ __forceinline__ void stage_tiles(const u16* __restrict__ Abase,
                                            const u16* __restrict__ Bbase,
                                            int K, int k0, u16* sAB, int tid, int wave) {
#pragma unroll
  for (int p = 0; p < 4; ++p) {
    int c = p * 256 + tid;          // 16B-chunk index in tile (1024 chunks)
    int row = c >> 3;
    size_t goff = (size_t)row * K + k0 + (c & 7) * 8;   // linear: coalesced DMA
    u16* la = sAB + (size_t)(p * 256 + wave * 64) * 8;  // wave-uniform base; HW adds lane*16
    __builtin_amdgcn_global_load_lds((const __attribute__((address_space(1))) void*)(Abase + goff),
                                     (__attribute__((address_space(3))) void*)la, 16, 0, 0);
    u16* lb = la + 8192;
    __builtin_amdgcn_global_load_lds((const __attribute__((address_space(1))) void*)(Bbase + goff),
                                     (__attribute__((address_space(3))) void*)lb, 16, 0, 0);
  }
}

// ---------- main GEMM: C = A·B^T + bias + 2*(T·Bl^T) (+gelu), software-pipelined ----------
// A,B inputs are pre-swizzled; LDS holds swizzled tile -> conflict-free ds_read_b128.
template<int DO_GELU>
__global__ __launch_bounds__(256)
void gemm_qlora_kernel(const u16* __restrict__ Ag, const u16* __restrict__ Bg,
                       const float* __restrict__ bias, const float* __restrict__ T,
                       const float* __restrict__ Bl, void* __restrict__ outp,
                       int M, int N, int K) {
  __shared__ u16 smem[4 * 8192];   // [buf][A/B][128*64]
  const int tid = threadIdx.x;
  const int wave = tid >> 6, lane = tid & 63;
  const int quad = lane >> 4, m16 = lane & 15;

  // square-tile swizzle: 64 consecutive ids cover an 8x8 (bm,bn) square
  const int num_n = N >> 7;
  const int nsq = num_n >> 3;
  int id = blockIdx.x;
  int sq = id >> 6, within = id & 63;
  int sqn = sq % nsq, sqm = sq / nsq;
  int bm = sqm * 8 + (within >> 3);
  int bn = sqn * 8 + (within & 7);

  const int wm = (wave >> 1) * 64, wn = (wave & 1) * 64;
  const u16* Abase = Ag + (size_t)bm * 128 * K;
  const u16* Bbase = Bg + (size_t)bn * 128 * K;

  floatx4 acc[4][4] = {};
  const int niter = K >> 6;

  stage_tiles(Abase, Bbase, K, 0, smem, tid, wave);   // prologue: tile 0 -> buf 0

  for (int it = 0; it < niter; ++it) {
    const int buf = it & 1;
    const u16* sA = smem + buf * 16384;
    const u16* sB = sA + 8192;

    // wait for this buf's DMA, raw barrier; prefetch issued after stays in flight.
    asm volatile("s_waitcnt vmcnt(0)\n\ts_barrier" ::: "memory");

    if (it + 1 < niter)
      stage_tiles(Abase, Bbase, K, (it + 1) << 6, smem + (buf ^ 1) * 16384, tid, wave);

#pragma unroll
    for (int kk = 0; kk < 2; ++kk) {
      int c8b = kk * 4 + quad;
      bf16x8 av[4], bv[4];
#pragma unroll
      for (int mt = 0; mt < 4; ++mt) {
        int row = wm + mt * 16 + m16;
        av[mt] = *(const bf16x8*)(sA + row * 64 + ((c8b ^ row) & 7) * 8);
      }
#pragma unroll
      for (int nt = 0; nt < 4; ++nt) {
        int row = wn + nt * 16 + m16;
        bv[nt] = *(const bf16x8*)(sB + row * 64 + ((c8b ^ row) & 7) * 8);
      }
#pragma unroll
      for (int mt = 0; mt < 4; ++mt)
#pragma unroll
        for (int nt = 0; nt < 4; ++nt)
          acc[mt][nt] = __builtin_amdgcn_mfma_f32_16x16x32_bf16(av[mt], bv[nt], acc[mt][nt], 0, 0, 0);
    }

    asm volatile("s_waitcnt lgkmcnt(0)\n\ts_barrier" ::: "memory");
  }

  // epilogue: C/D layout row=(lane>>4)*4+reg, col=lane&15
  const float* Trow = T + (size_t)bm * 128 * 16;
  const float* Blrow = Bl + (size_t)bn * 128 * 16;
#pragma unroll
  for (int mt = 0; mt < 4; ++mt) {
#pragma unroll
    for (int r = 0; r < 4; ++r) {
      int ml = wm + mt * 16 + quad * 4 + r;
      size_t gm = (size_t)bm * 128 + ml;
      const float4* tv = (const float4*)(Trow + (size_t)ml * 16);
      float4 ta = tv[0], tb = tv[1], tc = tv[2], td = tv[3];
#pragma unroll
      for (int nt = 0; nt < 4; ++nt) {
        int nl = wn + nt * 16 + m16;
        size_t gn = (size_t)bn * 128 + nl;
        const float4* bv4 = (const float4*)(Blrow + (size_t)nl * 16);
        float4 ba = bv4[0], bb = bv4[1], bc = bv4[2], bd = bv4[3];
        float lora = ta.x * ba.x + ta.y * ba.y + ta.z * ba.z + ta.w * ba.w
                   + tb.x * bb.x + tb.y * bb.y + tb.z * bb.z + tb.w * bb.w
                   + tc.x * bc.x + tc.y * bc.y + tc.z * bc.z + tc.w * bc.w
                   + td.x * bd.x + td.y * bd.y + td.z * bd.z + td.w * bd.w;
        float v = acc[mt][nt][r] + bias[gn] + LORA_SCALING * lora;
        if (DO_GELU) {
          float g = 0.5f * v * (1.0f + erff(v * 0.70710678118654752f));
          // store into SWIZZLED intermediate layout for the next GEMM's DMA
          size_t gcol = (gn & ~63ull) | ((((gn >> 3) ^ gm) & 7) << 3) | (gn & 7);
          ((u16*)outp)[gm * (size_t)N + gcol] = f2bf(g);
        } else {
          ((float*)outp)[gm * (size_t)N + gn] = v;
        }
      }
    }
  }
}

// ---------- launch ----------
extern "C" void kernel_launch(void* const* d_in, const int* in_sizes, int n_in,
                              void* d_out, int out_size, void* d_ws, size_t ws_size,
                              hipStream_t stream) {
  const float* x    = (const float*)d_in[0];
  const float* W_fc = (const float*)d_in[1];
  const float* b_fc = (const float*)d_in[2];
  const float* A_fc = (const float*)d_in[3];
  const float* B_fc = (const float*)d_in[4];
  const float* W_pr = (const float*)d_in[5];
  const float* b_pr = (const float*)d_in[6];
  const float* A_pr = (const float*)d_in[7];
  const float* B_pr = (const float*)d_in[8];
  float* out = (float*)d_out;

  const int F = in_sizes[2];                 // 4096
  const int D = in_sizes[6];                 // 1024
  const int M = in_sizes[0] / D;             // 8192
  int dsh = 0; while ((1 << dsh) < D) ++dsh; // log2(D)
  int fsh = 0; while ((1 << fsh) < F) ++fsh; // log2(F)

  char* ws = (char*)d_ws;
  unsigned* amax = (unsigned*)ws;            // [0]=fc, [1]=proj
  u16* wq_fc = (u16*)(ws + 1024);
  u16* wq_pr = wq_fc + (size_t)F * D;
  u16* xbf   = wq_pr + (size_t)D * F;
  u16* gbf   = xbf + (size_t)M * D;
  float* t1  = (float*)(gbf + (size_t)M * F);
  float* t2  = t1 + (size_t)M * 16;

  long long wfd4 = (long long)F * D / 4;
  long long wfd8 = (long long)F * D / 8;

  zero_ws_kernel<<<1, 64, 0, stream>>>(amax);
  absmax_kernel<<<1024, 256, 0, stream>>>(W_fc, wfd4, amax + 0);
  absmax_kernel<<<1024, 256, 0, stream>>>(W_pr, wfd4, amax + 1);
  quant_swz_kernel<<<2048, 256, 0, stream>>>(W_fc, amax + 0, wq_fc, wfd8, dsh - 3);
  quant_swz_kernel<<<2048, 256, 0, stream>>>(W_pr, amax + 1, wq_pr, wfd8, fsh - 3);
  f2bf_swz_kernel<<<2048, 256, 0, stream>>>(x, xbf, (long long)M * D / 8, dsh - 3);

  lora_t_kernel<<<M / 16, 256, 0, stream>>>(xbf, A_fc, t1, D);
  gemm_qlora_kernel<1><<<dim3((M / 128) * (F / 128)), 256, 0, stream>>>(
      xbf, wq_fc, b_fc, t1, B_fc, (void*)gbf, M, F, D);
  lora_t_kernel<<<M / 16, 256, 0, stream>>>(gbf, A_pr, t2, F);
  gemm_qlora_kernel<0><<<dim3((M / 128) * (D / 128)), 256, 0, stream>>>(
      gbf, wq_pr, b_pr, t2, B_pr, (void*)out, M, D, F);
}

// Round 4
// 896.262 us; speedup vs baseline: 1.0801x; 1.0801x over previous
//
#include <hip/hip_runtime.h>
#include <hip/hip_bf16.h>
#include <math.h>

typedef unsigned short u16;
typedef __bf16 bf16x8 __attribute__((ext_vector_type(8)));
typedef float floatx4 __attribute__((ext_vector_type(4)));

#define LORA_SCALING 2.0f   // alpha 32 / rank 16

// Swizzled intermediate layout: within each row and each 64-col (8x16B-chunk) group,
// stored chunk c8 holds original chunk c8 ^ (row & 7). GEMM staging DMA is linear;
// LDS tile ends up XOR-swizzled -> conflict-free ds_read_b128 fragment loads.

// ---------- helpers ----------
__device__ __forceinline__ u16 f2bf(float f) {
  unsigned u = __float_as_uint(f);
  u += 0x7fffu + ((u >> 16) & 1u);   // round-to-nearest-even
  return (u16)(u >> 16);
}
__device__ __forceinline__ float bflo(unsigned u) { return __uint_as_float(u << 16); }
__device__ __forceinline__ float bfhi(unsigned u) { return __uint_as_float(u & 0xffff0000u); }

// ---------- ws scale-slot zeroing ----------
__global__ void zero_ws_kernel(unsigned* p) {
  if (threadIdx.x < 16) p[threadIdx.x] = 0u;
}

// ---------- per-tensor absmax ----------
__global__ void absmax_kernel(const float* __restrict__ w, long long n4, unsigned* __restrict__ out) {
  long long i = (long long)blockIdx.x * blockDim.x + threadIdx.x;
  long long stride = (long long)gridDim.x * blockDim.x;
  float m = 0.f;
  for (; i < n4; i += stride) {
    float4 v = ((const float4*)w)[i];
    m = fmaxf(m, fmaxf(fmaxf(fabsf(v.x), fabsf(v.y)), fmaxf(fabsf(v.z), fabsf(v.w))));
  }
#pragma unroll
  for (int o = 32; o > 0; o >>= 1) m = fmaxf(m, __shfl_xor(m, o, 64));
  __shared__ float sm[8];
  int lane = threadIdx.x & 63, wv = threadIdx.x >> 6;
  if (lane == 0) sm[wv] = m;
  __syncthreads();
  if (threadIdx.x == 0) {
    float mm = sm[0];
    int nw = blockDim.x >> 6;
    for (int j = 1; j < nw; ++j) mm = fmaxf(mm, sm[j]);
    atomicMax(out, __float_as_uint(mm));
  }
}

// ---------- fake-quant W (fp32) -> bf16, XOR-swizzled layout ----------
__global__ void quant_swz_kernel(const float* __restrict__ w, const unsigned* __restrict__ amax,
                                 u16* __restrict__ wq, long long nchunk, int kshift3) {
  float am = __uint_as_float(*amax);
  float scale = am * (1.0f / 127.0f);
  float inv = 127.0f / am;
  long long c = (long long)blockIdx.x * blockDim.x + threadIdx.x;
  long long stride = (long long)gridDim.x * blockDim.x;
  for (; c < nchunk; c += stride) {
    long long row = c >> kshift3;
    long long src = (c & ~7ll) | ((c ^ row) & 7);
    const float4* s = (const float4*)(w + src * 8);
    float4 a = s[0], b = s[1];
    union { u16 h[8]; uint4 v; } o;
    o.h[0] = f2bf(fminf(fmaxf(rintf(a.x * inv), -128.f), 127.f) * scale);
    o.h[1] = f2bf(fminf(fmaxf(rintf(a.y * inv), -128.f), 127.f) * scale);
    o.h[2] = f2bf(fminf(fmaxf(rintf(a.z * inv), -128.f), 127.f) * scale);
    o.h[3] = f2bf(fminf(fmaxf(rintf(a.w * inv), -128.f), 127.f) * scale);
    o.h[4] = f2bf(fminf(fmaxf(rintf(b.x * inv), -128.f), 127.f) * scale);
    o.h[5] = f2bf(fminf(fmaxf(rintf(b.y * inv), -128.f), 127.f) * scale);
    o.h[6] = f2bf(fminf(fmaxf(rintf(b.z * inv), -128.f), 127.f) * scale);
    o.h[7] = f2bf(fminf(fmaxf(rintf(b.w * inv), -128.f), 127.f) * scale);
    ((uint4*)wq)[c] = o.v;
  }
}

// ---------- fp32 -> bf16, XOR-swizzled layout ----------
__global__ void f2bf_swz_kernel(const float* __restrict__ x, u16* __restrict__ xb,
                                long long nchunk, int kshift3) {
  long long c = (long long)blockIdx.x * blockDim.x + threadIdx.x;
  long long stride = (long long)gridDim.x * blockDim.x;
  for (; c < nchunk; c += stride) {
    long long row = c >> kshift3;
    long long src = (c & ~7ll) | ((c ^ row) & 7);
    const float4* s = (const float4*)(x + src * 8);
    float4 a = s[0], b = s[1];
    union { u16 h[8]; uint4 v; } o;
    o.h[0] = f2bf(a.x); o.h[1] = f2bf(a.y); o.h[2] = f2bf(a.z); o.h[3] = f2bf(a.w);
    o.h[4] = f2bf(b.x); o.h[5] = f2bf(b.y); o.h[6] = f2bf(b.z); o.h[7] = f2bf(b.w);
    ((uint4*)xb)[c] = o.v;
  }
}

// ---------- LoRA t = X(bf16, swizzled) @ A^T(fp32), rank 16, 2-stream ILP ----------
__global__ void lora_t_kernel(const u16* __restrict__ X, const float* __restrict__ A,
                              float* __restrict__ T, int K) {
  int r = threadIdx.x & 15;
  int mi = threadIdx.x >> 4;
  long long row = (long long)blockIdx.x * 16 + mi;
  int rp = (int)row & 7;
  const u16* xp = X + row * K;
  const float* ap = A + (long long)r * K;
  float acc0 = 0.f, acc1 = 0.f;
  for (int k = 0; k < K; k += 16) {
    int k2 = k + 8;
    int ka0 = (k & ~63) | ((((k >> 3) ^ rp) & 7) << 3);
    int ka1 = (k2 & ~63) | ((((k2 >> 3) ^ rp) & 7) << 3);
    uint4 x0 = *(const uint4*)(xp + ka0);
    uint4 x1 = *(const uint4*)(xp + ka1);
    float4 a0 = *(const float4*)(ap + k);
    float4 a1 = *(const float4*)(ap + k + 4);
    float4 a2 = *(const float4*)(ap + k2);
    float4 a3 = *(const float4*)(ap + k2 + 4);
    acc0 += bflo(x0.x) * a0.x + bfhi(x0.x) * a0.y + bflo(x0.y) * a0.z + bfhi(x0.y) * a0.w
          + bflo(x0.z) * a1.x + bfhi(x0.z) * a1.y + bflo(x0.w) * a1.z + bfhi(x0.w) * a1.w;
    acc1 += bflo(x1.x) * a2.x + bfhi(x1.x) * a2.y + bflo(x1.y) * a2.z + bfhi(x1.y) * a2.w
          + bflo(x1.z) * a3.x + bfhi(x1.z) * a3.y + bflo(x1.w) * a3.z + bfhi(x1.w) * a3.w;
  }
  T[row * 16 + r] = acc0 + acc1;
}

// ---------- staging: A tile 256x64 (32KB) + B tile 128x64 (16KB), linear DMA ----------
__device__ __forceinline__ void stage_tiles(const u16* __restrict__ Abase,
                                            const u16* __restrict__ Bbase,
                                            int K, int k0, u16* s, int tid, int wave) {
#pragma unroll
  for (int p = 0; p < 4; ++p) {
    int c = p * 512 + tid;                                // A chunk 0..2047
    size_t goff = (size_t)(c >> 3) * K + k0 + (c & 7) * 8;
    u16* l = s + (size_t)(p * 512 + wave * 64) * 8;       // wave-uniform base + lane*16B
    __builtin_amdgcn_global_load_lds((const __attribute__((address_space(1))) void*)(Abase + goff),
                                     (__attribute__((address_space(3))) void*)l, 16, 0, 0);
  }
#pragma unroll
  for (int p = 0; p < 2; ++p) {
    int c = p * 512 + tid;                                // B chunk 0..1023
    size_t goff = (size_t)(c >> 3) * K + k0 + (c & 7) * 8;
    u16* l = s + 16384 + (size_t)(p * 512 + wave * 64) * 8;
    __builtin_amdgcn_global_load_lds((const __attribute__((address_space(1))) void*)(Bbase + goff),
                                     (__attribute__((address_space(3))) void*)l, 16, 0, 0);
  }
}

// ---------- main GEMM: C = A·B^T + bias + 2*(T·Bl^T) (+gelu) ----------
// 256x128 tile, BK=64, 512 threads = 8 waves (4x2), each wave 4x4 frags of 16x16x32 bf16.
// Double-buffered LDS (96KB); raw barriers; prefetch issued before the drain wait.
// Grid: id&7 = XCD; XCD owns Mb/8 bm-tiles (strip stays L2-resident); bn sweeps slowly.
template<int DO_GELU>
__global__ __launch_bounds__(512, 2)
void gemm_qlora_kernel(const u16* __restrict__ Ag, const u16* __restrict__ Bg,
                       const float* __restrict__ bias, const float* __restrict__ T,
                       const float* __restrict__ Bl, void* __restrict__ outp,
                       int M, int N, int K) {
  __shared__ u16 smem[2 * 24576];   // [buf][A 16384 | B 8192]
  const int tid = threadIdx.x;
  const int wave = tid >> 6, lane = tid & 63;
  const int quad = lane >> 4, m16 = lane & 15;

  // XCD-partitioned mapping: Mb = M/256 (divisible by 8), per-XCD strip = Mb/8 rows.
  const int per = (M >> 8) >> 3;          // bm tiles per XCD (4 for M=8192)
  int j = blockIdx.x & 7, t = blockIdx.x >> 3;
  int bm = j * per + (t & (per - 1));     // bm-local fastest (per is power of 2: 4)
  int bn = t / per;

  const int wm = (wave >> 1) * 64, wn = (wave & 1) * 64;
  const u16* Abase = Ag + (size_t)bm * 256 * K;
  const u16* Bbase = Bg + (size_t)bn * 128 * K;

  floatx4 acc[4][4] = {};
  const int niter = K >> 6;

  stage_tiles(Abase, Bbase, K, 0, smem, tid, wave);   // prologue -> buf 0

  for (int it = 0; it < niter; ++it) {
    const int buf = it & 1;
    const u16* sA = smem + buf * 24576;
    const u16* sB = sA + 16384;

    if (it + 1 < niter) {
      // issue prefetch first, then wait only for the current tile's 6 DMA insts
      stage_tiles(Abase, Bbase, K, (it + 1) << 6, smem + (buf ^ 1) * 24576, tid, wave);
      asm volatile("s_waitcnt vmcnt(6)\n\ts_barrier" ::: "memory");
    } else {
      asm volatile("s_waitcnt vmcnt(0)\n\ts_barrier" ::: "memory");
    }

#pragma unroll
    for (int kk = 0; kk < 2; ++kk) {
      int c8b = kk * 4 + quad;
      bf16x8 av[4], bv[4];
#pragma unroll
      for (int mt = 0; mt < 4; ++mt) {
        int row = wm + mt * 16 + m16;
        av[mt] = *(const bf16x8*)(sA + row * 64 + ((c8b ^ row) & 7) * 8);
      }
#pragma unroll
      for (int nt = 0; nt < 4; ++nt) {
        int row = wn + nt * 16 + m16;
        bv[nt] = *(const bf16x8*)(sB + row * 64 + ((c8b ^ row) & 7) * 8);
      }
#pragma unroll
      for (int mt = 0; mt < 4; ++mt)
#pragma unroll
        for (int nt = 0; nt < 4; ++nt)
          acc[mt][nt] = __builtin_amdgcn_mfma_f32_16x16x32_bf16(av[mt], bv[nt], acc[mt][nt], 0, 0, 0);
    }

    // all LDS reads of this buf done across all waves -> safe for next DMA into it
    asm volatile("s_waitcnt lgkmcnt(0)\n\ts_barrier" ::: "memory");
  }

  // epilogue: C/D layout row=(lane>>4)*4+reg, col=lane&15
  const float* Trow = T + (size_t)bm * 256 * 16;
  const float* Blrow = Bl + (size_t)bn * 128 * 16;
#pragma unroll
  for (int mt = 0; mt < 4; ++mt) {
#pragma unroll
    for (int r = 0; r < 4; ++r) {
      int ml = wm + mt * 16 + quad * 4 + r;
      size_t gm = (size_t)bm * 256 + ml;
      const float4* tv = (const float4*)(Trow + (size_t)ml * 16);
      float4 ta = tv[0], tb = tv[1], tc = tv[2], td = tv[3];
#pragma unroll
      for (int nt = 0; nt < 4; ++nt) {
        int nl = wn + nt * 16 + m16;
        size_t gn = (size_t)bn * 128 + nl;
        const float4* bv4 = (const float4*)(Blrow + (size_t)nl * 16);
        float4 ba = bv4[0], bb = bv4[1], bc = bv4[2], bd = bv4[3];
        float lora = ta.x * ba.x + ta.y * ba.y + ta.z * ba.z + ta.w * ba.w
                   + tb.x * bb.x + tb.y * bb.y + tb.z * bb.z + tb.w * bb.w
                   + tc.x * bc.x + tc.y * bc.y + tc.z * bc.z + tc.w * bc.w
                   + td.x * bd.x + td.y * bd.y + td.z * bd.z + td.w * bd.w;
        float v = acc[mt][nt][r] + bias[gn] + LORA_SCALING * lora;
        if (DO_GELU) {
          float g = 0.5f * v * (1.0f + erff(v * 0.70710678118654752f));
          size_t gcol = (gn & ~63ull) | ((((gn >> 3) ^ gm) & 7) << 3) | (gn & 7);
          ((u16*)outp)[gm * (size_t)N + gcol] = f2bf(g);
        } else {
          ((float*)outp)[gm * (size_t)N + gn] = v;
        }
      }
    }
  }
}

// ---------- launch ----------
extern "C" void kernel_launch(void* const* d_in, const int* in_sizes, int n_in,
                              void* d_out, int out_size, void* d_ws, size_t ws_size,
                              hipStream_t stream) {
  const float* x    = (const float*)d_in[0];
  const float* W_fc = (const float*)d_in[1];
  const float* b_fc = (const float*)d_in[2];
  const float* A_fc = (const float*)d_in[3];
  const float* B_fc = (const float*)d_in[4];
  const float* W_pr = (const float*)d_in[5];
  const float* b_pr = (const float*)d_in[6];
  const float* A_pr = (const float*)d_in[7];
  const float* B_pr = (const float*)d_in[8];
  float* out = (float*)d_out;

  const int F = in_sizes[2];                 // 4096
  const int D = in_sizes[6];                 // 1024
  const int M = in_sizes[0] / D;             // 8192
  int dsh = 0; while ((1 << dsh) < D) ++dsh;
  int fsh = 0; while ((1 << fsh) < F) ++fsh;

  char* ws = (char*)d_ws;
  unsigned* amax = (unsigned*)ws;
  u16* wq_fc = (u16*)(ws + 1024);
  u16* wq_pr = wq_fc + (size_t)F * D;
  u16* xbf   = wq_pr + (size_t)D * F;
  u16* gbf   = xbf + (size_t)M * D;
  float* t1  = (float*)(gbf + (size_t)M * F);
  float* t2  = t1 + (size_t)M * 16;

  long long wfd4 = (long long)F * D / 4;
  long long wfd8 = (long long)F * D / 8;

  zero_ws_kernel<<<1, 64, 0, stream>>>(amax);
  absmax_kernel<<<1024, 256, 0, stream>>>(W_fc, wfd4, amax + 0);
  absmax_kernel<<<1024, 256, 0, stream>>>(W_pr, wfd4, amax + 1);
  quant_swz_kernel<<<2048, 256, 0, stream>>>(W_fc, amax + 0, wq_fc, wfd8, dsh - 3);
  quant_swz_kernel<<<2048, 256, 0, stream>>>(W_pr, amax + 1, wq_pr, wfd8, fsh - 3);
  f2bf_swz_kernel<<<2048, 256, 0, stream>>>(x, xbf, (long long)M * D / 8, dsh - 3);

  lora_t_kernel<<<M / 16, 256, 0, stream>>>(xbf, A_fc, t1, D);
  gemm_qlora_kernel<1><<<dim3((M / 256) * (F / 128)), 512, 0, stream>>>(
      xbf, wq_fc, b_fc, t1, B_fc, (void*)gbf, M, F, D);
  lora_t_kernel<<<M / 16, 256, 0, stream>>>(gbf, A_pr, t2, F);
  gemm_qlora_kernel<0><<<dim3((M / 256) * (D / 128)), 512, 0, stream>>>(
      gbf, wq_pr, b_pr, t2, B_pr, (void*)out, M, D, F);
}